// Round 1
// baseline (1965.496 us; speedup 1.0000x reference)
//
#include <hip/hip_runtime.h>
#include <math.h>

#define DEV static __device__ __forceinline__

constexpr int NN = 8192;    // nodes
constexpr int NE = 32768;   // edges
constexpr int NB = 32;      // graphs

DEV int lidx_of(int c) { return (c == 0) ? 0 : (c < 4) ? 1 : (c < 9) ? 2 : 3; }

DEV void real_sh_f(float x, float y, float z, float* Y) {
  const float s3  = 1.7320508075688772f;
  const float s5  = 2.23606797749979f;
  const float s15 = 3.872983346207417f;
  Y[0] = 1.f;
  Y[1] = s3 * y;  Y[2] = s3 * z;  Y[3] = s3 * x;
  Y[4] = s15 * x * y;
  Y[5] = s15 * y * z;
  Y[6] = 0.5f * s5 * (3.f * z * z - 1.f);
  Y[7] = s15 * x * z;
  Y[8] = 0.5f * s15 * (x * x - y * y);
  Y[9]  = 2.091650066335189f * y * (3.f * x * x - y * y);
  Y[10] = 10.246950765959598f * x * y * z;
  Y[11] = 1.6201851746019651f * y * (5.f * z * z - 1.f);
  Y[12] = 1.3228756555322954f * (5.f * z * z * z - 3.f * z);
  Y[13] = 1.6201851746019651f * x * (5.f * z * z - 1.f);
  Y[14] = 5.123475382979799f * (x * x - y * y) * z;
  Y[15] = 2.091650066335189f * x * (x * x - 3.f * y * y);
}

// ---------------- edge geometry: Y, u, cut + degree histogram ----------------
__global__ __launch_bounds__(256) void k_edge_prep(
    const float* __restrict__ pos, const int* __restrict__ esrc,
    const int* __restrict__ edst, float* __restrict__ u_, float* __restrict__ cut_,
    float* __restrict__ Y_, int* __restrict__ cnt) {
  const int e = blockIdx.x * 256 + threadIdx.x;
  if (e >= NE) return;
  const int s = esrc[e], t = edst[e];
  const float ex = pos[t * 3 + 0] - pos[s * 3 + 0];
  const float ey = pos[t * 3 + 1] - pos[s * 3 + 1];
  const float ez = pos[t * 3 + 2] - pos[s * 3 + 2];
  const float d = sqrtf(ex * ex + ey * ey + ez * ez) + 1e-9f;
  const float inv = 1.f / d;
  float Y[16];
  real_sh_f(ex * inv, ey * inv, ez * inv, Y);
#pragma unroll
  for (int c = 0; c < 16; ++c) Y_[(size_t)e * 16 + c] = Y[c];
  const float u = d / 3.5f;
  u_[e] = u;
  cut_[e] = (u < 1.f) ? 0.5f * (cosf(3.14159265358979323846f * u) + 1.f) : 0.f;
  atomicAdd(&cnt[t], 1);
}

// ---------------- CSR build: scan + fill ----------------
__global__ __launch_bounds__(256) void k_scan(const int* __restrict__ cnt,
                                              int* __restrict__ offs,
                                              int* __restrict__ cursor) {
  __shared__ int part[256];
  const int t = threadIdx.x;
  int s = 0;
  for (int i = 0; i < 32; ++i) s += cnt[t * 32 + i];
  part[t] = s;
  __syncthreads();
  if (t == 0) {
    int run = 0;
    for (int i = 0; i < 256; ++i) { int v = part[i]; part[i] = run; run += v; }
    offs[NN] = run;
  }
  __syncthreads();
  int run = part[t];
  for (int i = 0; i < 32; ++i) {
    const int idx = t * 32 + i;
    offs[idx] = run;
    cursor[idx] = run;
    run += cnt[idx];
  }
}

__global__ __launch_bounds__(256) void k_fill(const int* __restrict__ edst,
                                              int* __restrict__ cursor,
                                              int* __restrict__ elist) {
  const int e = blockIdx.x * 256 + threadIdx.x;
  if (e < NE) {
    const int p = atomicAdd(&cursor[edst[e]], 1);
    elist[p] = e;
  }
}

// ---------------- per-edge bilinear GEMM: t[e][128] (and optional self[e][128]) ----
// t[e,o] = scale * sum_{k<64,f<16} hh[e,k]*feat16[src,f] * W2row(k,f)[o]
// W2 row base: msg1 -> (k*16+f)*128 ; msg2 -> k*2176 + f*128 (cols 0..2047 of rad2_W2)
// self (msg2 only): self[e,o] = 0.5 * sum_k hh[e,k] * rad2_W2[k][2048+o]
template <bool IS2>
__global__ __launch_bounds__(256) void k_msg(
    const float* __restrict__ u_, const float* __restrict__ cut_,
    const float* __restrict__ W1, const float* __restrict__ bvec,
    const float* __restrict__ W2, const float* __restrict__ feat16,
    const int* __restrict__ esrc, float* __restrict__ t_, float* __restrict__ self_) {
  __shared__ __align__(16) float hhL[64][65];
  __shared__ __align__(16) float nfL[64][17];
  __shared__ __align__(16) float BL[64][128];
  __shared__ float uL[64], cL[64];
  __shared__ int sL[64];
  const int tid = threadIdx.x;
  const int e0 = blockIdx.x * 64;
  if (tid < 64) {
    uL[tid] = u_[e0 + tid];
    cL[tid] = cut_[e0 + tid];
    sL[tid] = esrc[e0 + tid];
  }
  __syncthreads();
  for (int i = tid; i < 64 * 64; i += 256) {
    const int e = i >> 6, k = i & 63;
    hhL[e][k] = fmaxf(fmaf(uL[e], W1[k], bvec[k]), 0.f) * cL[e];
  }
  for (int i = tid; i < 64 * 16; i += 256) {
    const int e = i >> 4, f = i & 15;
    nfL[e][f] = feat16[(size_t)sL[e] * 16 + f];
  }
  const int ty = tid >> 4, tx = tid & 15;
  float acc[4][8];
#pragma unroll
  for (int a = 0; a < 4; ++a)
#pragma unroll
    for (int o = 0; o < 8; ++o) acc[a][o] = 0.f;

  for (int ch = 0; ch < 16; ++ch) {
    __syncthreads();
#pragma unroll
    for (int j = 0; j < 8; ++j) {
      const int q = tid + j * 256;
      const int row = q >> 5, c4 = (q & 31) << 2;
      const int kf = ch * 64 + row;
      size_t gaddr;
      if (IS2) gaddr = (size_t)(kf >> 4) * 2176 + (size_t)(kf & 15) * 128 + c4;
      else     gaddr = (size_t)kf * 128 + c4;
      *(float4*)&BL[row][c4] = *(const float4*)(W2 + gaddr);
    }
    __syncthreads();
#pragma unroll
    for (int kk = 0; kk < 4; ++kk) {
      const int k = ch * 4 + kk;
      float ha[4];
#pragma unroll
      for (int a = 0; a < 4; ++a) ha[a] = hhL[ty * 4 + a][k];
#pragma unroll
      for (int f = 0; f < 16; ++f) {
        float av[4];
#pragma unroll
        for (int a = 0; a < 4; ++a) av[a] = ha[a] * nfL[ty * 4 + a][f];
        const float* Br = &BL[kk * 16 + f][tx * 8];
#pragma unroll
        for (int o = 0; o < 8; ++o) {
          const float bv = Br[o];
#pragma unroll
          for (int a = 0; a < 4; ++a) acc[a][o] = fmaf(av[a], bv, acc[a][o]);
        }
      }
    }
  }
#pragma unroll
  for (int a = 0; a < 4; ++a) {
    float* op = &t_[(size_t)(e0 + ty * 4 + a) * 128 + tx * 8];
#pragma unroll
    for (int o = 0; o < 8; ++o) op[o] = acc[a][o] * 0.125f;  // 1/sqrt(F)/deg
  }

  if (IS2) {
    __syncthreads();
#pragma unroll
    for (int j = 0; j < 8; ++j) {
      const int q = tid + j * 256;
      const int row = q >> 5, c4 = (q & 31) << 2;
      *(float4*)&BL[row][c4] = *(const float4*)(W2 + (size_t)row * 2176 + 2048 + c4);
    }
    __syncthreads();
    float sacc[4][8];
#pragma unroll
    for (int a = 0; a < 4; ++a)
#pragma unroll
      for (int o = 0; o < 8; ++o) sacc[a][o] = 0.f;
    for (int k = 0; k < 64; ++k) {
      float ha[4];
#pragma unroll
      for (int a = 0; a < 4; ++a) ha[a] = hhL[ty * 4 + a][k];
      const float* Br = &BL[k][tx * 8];
#pragma unroll
      for (int o = 0; o < 8; ++o) {
        const float bv = Br[o];
#pragma unroll
        for (int a = 0; a < 4; ++a) sacc[a][o] = fmaf(ha[a], bv, sacc[a][o]);
      }
    }
#pragma unroll
    for (int a = 0; a < 4; ++a) {
      float* op = &self_[(size_t)(e0 + ty * 4 + a) * 128 + tx * 8];
#pragma unroll
      for (int o = 0; o < 8; ++o) op[o] = sacc[a][o] * 0.5f;  // 1/deg
    }
  }
}

// ---------------- gather (segment sum over incoming edges) + gate ----------------
__global__ __launch_bounds__(256) void k_gather1(
    const float* __restrict__ t_, const float* __restrict__ Y_,
    const int* __restrict__ offs, const int* __restrict__ elist,
    float* __restrict__ h1, float* __restrict__ h1s) {
  __shared__ float tL[128], YL[16], sG[32];
  const int n = blockIdx.x, tid = threadIdx.x;
  const int beg = offs[n], end = offs[n + 1];
  const int cc = tid & 15;
  const int lx = lidx_of(cc);
  const int o0 = ((tid >> 4) << 2) + lx;
  const int o1 = o0 + 64;
  float a0 = 0.f, a1 = 0.f;
  for (int ei = beg; ei < end; ++ei) {
    const int e = elist[ei];
    __syncthreads();
    if (tid < 128) tL[tid] = t_[(size_t)e * 128 + tid];
    else if (tid < 144) YL[tid - 128] = Y_[(size_t)e * 16 + tid - 128];
    __syncthreads();
    const float yv = YL[cc];
    a0 = fmaf(tL[o0], yv, a0);
    a1 = fmaf(tL[o1], yv, a1);
  }
  if (cc == 0) { sG[tid >> 4] = a0; sG[(tid >> 4) + 16] = a1; }
  __syncthreads();
  const float s0 = sG[tid >> 4], s1 = sG[(tid >> 4) + 16];
  const float r0 = (cc == 0) ? fmaxf(a0, 0.f) : a0 * (1.f / (1.f + expf(-s0)));
  const float r1 = (cc == 0) ? fmaxf(a1, 0.f) : a1 * (1.f / (1.f + expf(-s1)));
  h1[(size_t)n * 512 + tid] = r0;
  h1[(size_t)n * 512 + tid + 256] = r1;
  if ((tid & 31) == 0) {
    h1s[n * 16 + (tid >> 5)] = r0;       // g = 0..7  (p=0,c=0)
    h1s[n * 16 + (tid >> 5) + 8] = r1;   // g = 8..15
  }
}

__global__ __launch_bounds__(256) void k_gather2(
    const float* __restrict__ t_, const float* __restrict__ self_,
    const float* __restrict__ Y_, const float* __restrict__ h1,
    const int* __restrict__ offs, const int* __restrict__ elist,
    const int* __restrict__ esrc, float* __restrict__ h2) {
  __shared__ float tL[128], wL[128], YL[16], sG[32];
  const int n = blockIdx.x, tid = threadIdx.x;
  const int beg = offs[n], end = offs[n + 1];
  const int cc = tid & 15;
  const int lx = lidx_of(cc);
  const int o0 = ((tid >> 4) << 2) + lx;
  const int o1 = o0 + 64;
  float a0 = 0.f, a1 = 0.f;
  for (int ei = beg; ei < end; ++ei) {
    const int e = elist[ei];
    __syncthreads();
    if (tid < 128) tL[tid] = t_[(size_t)e * 128 + tid];
    else wL[tid - 128] = self_[(size_t)e * 128 + tid - 128];
    if (tid < 16) YL[tid] = Y_[(size_t)e * 16 + tid];
    __syncthreads();
    const int src = esrc[e];
    const float* hr = &h1[(size_t)src * 512];
    const float yv = YL[cc];
    a0 += tL[o0] * yv + hr[tid] * wL[o0];
    a1 += tL[o1] * yv + hr[tid + 256] * wL[o1];
  }
  if (cc == 0) { sG[tid >> 4] = a0; sG[(tid >> 4) + 16] = a1; }
  __syncthreads();
  const float s0 = sG[tid >> 4], s1 = sG[(tid >> 4) + 16];
  const float r0 = (cc == 0) ? fmaxf(a0, 0.f) : a0 * (1.f / (1.f + expf(-s0)));
  const float r1 = (cc == 0) ? fmaxf(a1, 0.f) : a1 * (1.f / (1.f + expf(-s1)));
  h2[(size_t)n * 512 + tid] = r0;
  h2[(size_t)n * 512 + tid + 256] = r1;
}

// ---------------- mean pool over each graph's 256 nodes ----------------
__global__ __launch_bounds__(256) void k_pool(const float* __restrict__ h2,
                                              float* __restrict__ enc) {
  const int b = blockIdx.x, tid = threadIdx.x;
  float a0 = 0.f, a1 = 0.f;
  for (int i = 0; i < 256; ++i) {
    const float* row = &h2[(size_t)(b * 256 + i) * 512];
    a0 += row[tid];
    a1 += row[tid + 256];
  }
  enc[b * 512 + tid] = a0 * (1.f / 256.f);
  enc[b * 512 + tid + 256] = a1 * (1.f / 256.f);
}

// ---------------- z = per-l linear mix of enc (B,32,16) -> (B,16,84) ----------------
__global__ __launch_bounds__(256) void k_zproj(const float* __restrict__ enc,
                                               const float* __restrict__ Wlin,
                                               float* __restrict__ z) {
  __shared__ float eL[512];
  const int b = blockIdx.x, tid = threadIdx.x;
  eL[tid] = enc[b * 512 + tid];
  eL[tid + 256] = enc[b * 512 + tid + 256];
  __syncthreads();
  for (int idx = tid; idx < 16 * 84; idx += 256) {
    const int g = idx / 84, d3 = idx % 84;
    int o0, m0, mo;
    if (d3 < 1)       { o0 = 0;  m0 = 1; mo = 0; }
    else if (d3 < 10) { o0 = 1;  m0 = 3; mo = 1; }
    else if (d3 < 35) { o0 = 10; m0 = 5; mo = 4; }
    else              { o0 = 35; m0 = 7; mo = 9; }
    const int rem = d3 - o0;
    const int jj = rem / m0;
    const int cc2 = rem - jj * m0;
    float a = 0.f;
    for (int mu = 0; mu < 32; ++mu)
      a = fmaf(eL[mu * 16 + mo + cc2], Wlin[(mu * 16 + g) * 16 + mo + jj], a);
    z[(size_t)(b * 16 + g) * 84 + d3] = a * 0.17677669529663687f;  // 1/sqrt(32)
  }
}

// ---------------- SO3 conv: per-l matmul ----------------
template <int M, int FI, int FO>
DEV void conv_item(const float* xL, const float* __restrict__ psi, int b, int g,
                   int o0, int j, float* __restrict__ out, float scale) {
  float acc[M];
#pragma unroll
  for (int c = 0; c < M; ++c) acc[c] = 0.f;
  for (int f = 0; f < FI; ++f) {
    const float* xr = &xL[f * 84 + o0];
    const float* pr = &psi[((size_t)f * FO + g) * 84 + o0 + j];
#pragma unroll
    for (int i = 0; i < M; ++i) {
      const float pv = pr[i * M];
#pragma unroll
      for (int c = 0; c < M; ++c) acc[c] = fmaf(xr[i * M + c], pv, acc[c]);
    }
  }
  float* op = &out[((size_t)b * FO + g) * 84 + o0 + j * M];
#pragma unroll
  for (int c = 0; c < M; ++c) op[c] = acc[c] * scale;
}

template <int FI, int FO>
__global__ __launch_bounds__(256) void k_conv(const float* __restrict__ x,
                                              const float* __restrict__ psi,
                                              float* __restrict__ out) {
  __shared__ float xL[FI * 84];
  const int tid = threadIdx.x, b = blockIdx.x;
  for (int i = tid; i < FI * 84; i += 256) xL[i] = x[(size_t)b * FI * 84 + i];
  __syncthreads();
  const int g0 = blockIdx.y * 16;
  // items ordered by l so waves stay mostly convergent:
  // [0,16): l=0 ; [16,64): l=1 ; [64,144): l=2 ; [144,256): l=3
  if (tid < 16) {
    conv_item<1, FI, FO>(xL, psi, b, g0 + tid, 0, 0, out, 1.f / sqrtf((float)(FI * 1)));
  } else if (tid < 64) {
    const int q = tid - 16;
    conv_item<3, FI, FO>(xL, psi, b, g0 + q / 3, 1, q % 3, out, 1.f / sqrtf((float)(FI * 3)));
  } else if (tid < 144) {
    const int q = tid - 64;
    conv_item<5, FI, FO>(xL, psi, b, g0 + q / 5, 10, q % 5, out, 1.f / sqrtf((float)(FI * 5)));
  } else {
    const int q = tid - 144;
    conv_item<7, FI, FO>(xL, psi, b, g0 + q / 7, 35, q % 7, out, 1.f / sqrtf((float)(FI * 7)));
  }
}

// ---------------- SO3 act: out = (relu(x@G_to) @ G_from) * scale, fused ----------------
template <int RB>
__global__ __launch_bounds__(256) void k_act(const float* __restrict__ x,
                                             const float* __restrict__ Gt,
                                             const float* __restrict__ Gf,
                                             float* __restrict__ out) {
  __shared__ float yL[RB][84];
  __shared__ float gch[RB][257];
  const int tid = threadIdx.x;
  const int r0 = blockIdx.x * RB;
  for (int i = tid; i < RB * 84; i += 256) yL[i / 84][i % 84] = x[(size_t)r0 * 84 + i];
  __syncthreads();
  constexpr int NP = (RB * 84 + 255) / 256;
  float acc[NP];
#pragma unroll
  for (int s = 0; s < NP; ++s) acc[s] = 0.f;
  for (int cc = 0; cc < 16; ++cc) {
    const int gg = cc * 256 + tid;
    float fa[RB];
#pragma unroll
    for (int r = 0; r < RB; ++r) fa[r] = 0.f;
    for (int d = 0; d < 84; ++d) {
      const float gt = Gt[(size_t)d * 4096 + gg];
#pragma unroll
      for (int r = 0; r < RB; ++r) fa[r] = fmaf(yL[r][d], gt, fa[r]);
    }
    __syncthreads();  // prior phase-2 readers done
#pragma unroll
    for (int r = 0; r < RB; ++r) gch[r][tid] = fmaxf(fa[r], 0.f);
    __syncthreads();
#pragma unroll
    for (int s = 0; s < NP; ++s) {
      const int idx = tid + s * 256;
      if (idx < RB * 84) {
        const int r = idx / 84, d = idx % 84;
        const float* gfp = &Gf[(size_t)(cc * 256) * 84 + d];
        float a = 0.f;
        for (int g2 = 0; g2 < 256; ++g2) a = fmaf(gch[r][g2], gfp[(size_t)g2 * 84], a);
        acc[s] += a;
      }
    }
  }
  const float sc = 1.f / (sqrtf(84.f) * 64.f);
#pragma unroll
  for (int s = 0; s < NP; ++s) {
    const int idx = tid + s * 256;
    if (idx < RB * 84) out[(size_t)r0 * 84 + idx] = acc[s] * sc;
  }
}

// ---------------- final: Ws2 contraction + orientation SH dot ----------------
__global__ __launch_bounds__(256) void k_final(const float* __restrict__ x,
                                               const float* __restrict__ Ws2,
                                               const float* __restrict__ orient,
                                               float* __restrict__ outp) {
  __shared__ float red[256][16];
  const int b = blockIdx.x, tid = threadIdx.x;
  const float* xr = &x[(size_t)(b * 256 + tid) * 84];
  const float* wr = &Ws2[tid * 16];
  float acc[16];
#pragma unroll
  for (int c = 0; c < 16; ++c) acc[c] = 0.f;
  acc[0] = fmaf(xr[0], wr[0], acc[0]);
#pragma unroll
  for (int i = 0; i < 3; ++i) {
    const float w = wr[1 + i];
#pragma unroll
    for (int c = 0; c < 3; ++c) acc[1 + c] = fmaf(xr[1 + i * 3 + c], w, acc[1 + c]);
  }
#pragma unroll
  for (int i = 0; i < 5; ++i) {
    const float w = wr[4 + i];
#pragma unroll
    for (int c = 0; c < 5; ++c) acc[4 + c] = fmaf(xr[10 + i * 5 + c], w, acc[4 + c]);
  }
#pragma unroll
  for (int i = 0; i < 7; ++i) {
    const float w = wr[9 + i];
#pragma unroll
    for (int c = 0; c < 7; ++c) acc[9 + c] = fmaf(xr[35 + i * 7 + c], w, acc[9 + c]);
  }
#pragma unroll
  for (int c = 0; c < 16; ++c) red[tid][c] = acc[c];
  __syncthreads();
  for (int off = 128; off > 0; off >>= 1) {
    if (tid < off)
#pragma unroll
      for (int c = 0; c < 16; ++c) red[tid][c] += red[tid + off][c];
    __syncthreads();
  }
  if (tid == 0) {
    const float aa = orient[b * 2 + 0], rr = orient[b * 2 + 1];
    float Y[16];
    real_sh_f(-sinf(aa) * cosf(rr), -sinf(aa) * sinf(rr), -cosf(aa), Y);
    const float sc1 = 1.f / 16.f;
    const float sc3 = 1.f / (16.f * 1.7320508075688772f);
    const float sc5 = 1.f / (16.f * 2.23606797749979f);
    const float sc7 = 1.f / (16.f * 2.6457513110645907f);
    float o = red[0][0] * sc1 * Y[0];
#pragma unroll
    for (int c = 1; c < 4; ++c) o += red[0][c] * sc3 * Y[c];
#pragma unroll
    for (int c = 4; c < 9; ++c) o += red[0][c] * sc5 * Y[c];
#pragma unroll
    for (int c = 9; c < 16; ++c) o += red[0][c] * sc7 * Y[c];
    outp[b] = o;
  }
}

extern "C" void kernel_launch(void* const* d_in, const int* in_sizes, int n_in,
                              void* d_out, int out_size, void* d_ws, size_t ws_size,
                              hipStream_t stream) {
  const float* node_feat = (const float*)d_in[0];
  const float* pos       = (const float*)d_in[1];
  const float* orient    = (const float*)d_in[2];
  const float* rad1_W1   = (const float*)d_in[3];
  const float* rad1_b    = (const float*)d_in[4];
  const float* rad1_W2   = (const float*)d_in[5];
  const float* rad2_W1   = (const float*)d_in[6];
  const float* rad2_b    = (const float*)d_in[7];
  const float* rad2_W2   = (const float*)d_in[8];
  const float* Wlin      = (const float*)d_in[9];
  const float* psi1      = (const float*)d_in[10];
  const float* psi2      = (const float*)d_in[11];
  const float* psi3      = (const float*)d_in[12];
  const float* G_to      = (const float*)d_in[13];
  const float* G_from    = (const float*)d_in[14];
  const float* Ws2       = (const float*)d_in[15];
  const int*   esrc      = (const int*)d_in[16];
  const int*   edst      = (const int*)d_in[17];

  float* w = (float*)d_ws;
  size_t off = 0;
  float* u_    = w + off; off += NE;
  float* cut_  = w + off; off += NE;
  float* Y_    = w + off; off += (size_t)NE * 16;
  float* t_    = w + off; off += (size_t)NE * 128;   // t1, then reused for t2
  float* self_ = w + off; off += (size_t)NE * 128;
  float* h1    = w + off; off += (size_t)NN * 512;
  float* h1s   = w + off; off += (size_t)NN * 16;
  float* h2    = w + off; off += (size_t)NN * 512;
  float* enc   = w + off; off += (size_t)NB * 512;
  float* z     = w + off; off += (size_t)NB * 16 * 84;
  float* xb1   = w + off; off += (size_t)NB * 256 * 84;
  float* xb2   = w + off; off += (size_t)NB * 256 * 84;
  int* cnt    = (int*)(w + off); off += NN;
  int* offs   = (int*)(w + off); off += NN + 1;
  int* cursor = (int*)(w + off); off += NN;
  int* elist  = (int*)(w + off); off += NE;
  // total ~76 MB of workspace

  hipMemsetAsync(cnt, 0, NN * sizeof(int), stream);
  k_edge_prep<<<NE / 256, 256, 0, stream>>>(pos, esrc, edst, u_, cut_, Y_, cnt);
  k_scan<<<1, 256, 0, stream>>>(cnt, offs, cursor);
  k_fill<<<NE / 256, 256, 0, stream>>>(edst, cursor, elist);
  k_msg<false><<<NE / 64, 256, 0, stream>>>(u_, cut_, rad1_W1, rad1_b, rad1_W2,
                                            node_feat, esrc, t_, nullptr);
  k_gather1<<<NN, 256, 0, stream>>>(t_, Y_, offs, elist, h1, h1s);
  k_msg<true><<<NE / 64, 256, 0, stream>>>(u_, cut_, rad2_W1, rad2_b, rad2_W2,
                                           h1s, esrc, t_, self_);
  k_gather2<<<NN, 256, 0, stream>>>(t_, self_, Y_, h1, offs, elist, esrc, h2);
  k_pool<<<NB, 256, 0, stream>>>(h2, enc);
  k_zproj<<<NB, 256, 0, stream>>>(enc, Wlin, z);
  k_conv<16, 64><<<dim3(NB, 4), 256, 0, stream>>>(z, psi1, xb1);
  k_act<8><<<(NB * 64) / 8, 256, 0, stream>>>(xb1, G_to, G_from, xb2);
  k_conv<64, 128><<<dim3(NB, 8), 256, 0, stream>>>(xb2, psi2, xb1);
  k_act<16><<<(NB * 128) / 16, 256, 0, stream>>>(xb1, G_to, G_from, xb2);
  k_conv<128, 256><<<dim3(NB, 16), 256, 0, stream>>>(xb2, psi3, xb1);
  k_act<32><<<(NB * 256) / 32, 256, 0, stream>>>(xb1, G_to, G_from, xb2);
  k_final<<<NB, 256, 0, stream>>>(xb2, Ws2, orient, (float*)d_out);
}

// Round 2
// 908.560 us; speedup vs baseline: 2.1633x; 2.1633x over previous
//
#include <hip/hip_runtime.h>
#include <math.h>

#define DEV static __device__ __forceinline__

constexpr int NN = 8192;    // nodes
constexpr int NE = 32768;   // edges
constexpr int NB = 32;      // graphs

DEV int lidx_of(int c) { return (c == 0) ? 0 : (c < 4) ? 1 : (c < 9) ? 2 : 3; }

DEV void real_sh_f(float x, float y, float z, float* Y) {
  const float s3  = 1.7320508075688772f;
  const float s5  = 2.23606797749979f;
  const float s15 = 3.872983346207417f;
  Y[0] = 1.f;
  Y[1] = s3 * y;  Y[2] = s3 * z;  Y[3] = s3 * x;
  Y[4] = s15 * x * y;
  Y[5] = s15 * y * z;
  Y[6] = 0.5f * s5 * (3.f * z * z - 1.f);
  Y[7] = s15 * x * z;
  Y[8] = 0.5f * s15 * (x * x - y * y);
  Y[9]  = 2.091650066335189f * y * (3.f * x * x - y * y);
  Y[10] = 10.246950765959598f * x * y * z;
  Y[11] = 1.6201851746019651f * y * (5.f * z * z - 1.f);
  Y[12] = 1.3228756555322954f * (5.f * z * z * z - 3.f * z);
  Y[13] = 1.6201851746019651f * x * (5.f * z * z - 1.f);
  Y[14] = 5.123475382979799f * (x * x - y * y) * z;
  Y[15] = 2.091650066335189f * x * (x * x - 3.f * y * y);
}

// ---------------- edge geometry: Y, u, cut + degree histogram ----------------
__global__ __launch_bounds__(256) void k_edge_prep(
    const float* __restrict__ pos, const int* __restrict__ esrc,
    const int* __restrict__ edst, float* __restrict__ u_, float* __restrict__ cut_,
    float* __restrict__ Y_, int* __restrict__ cnt) {
  const int e = blockIdx.x * 256 + threadIdx.x;
  if (e >= NE) return;
  const int s = esrc[e], t = edst[e];
  const float ex = pos[t * 3 + 0] - pos[s * 3 + 0];
  const float ey = pos[t * 3 + 1] - pos[s * 3 + 1];
  const float ez = pos[t * 3 + 2] - pos[s * 3 + 2];
  const float d = sqrtf(ex * ex + ey * ey + ez * ez) + 1e-9f;
  const float inv = 1.f / d;
  float Y[16];
  real_sh_f(ex * inv, ey * inv, ez * inv, Y);
#pragma unroll
  for (int c = 0; c < 16; ++c) Y_[(size_t)e * 16 + c] = Y[c];
  const float u = d / 3.5f;
  u_[e] = u;
  cut_[e] = (u < 1.f) ? 0.5f * (cosf(3.14159265358979323846f * u) + 1.f) : 0.f;
  atomicAdd(&cnt[t], 1);
}

// ---------------- CSR build: scan + fill ----------------
__global__ __launch_bounds__(256) void k_scan(const int* __restrict__ cnt,
                                              int* __restrict__ offs,
                                              int* __restrict__ cursor) {
  __shared__ int part[256];
  const int t = threadIdx.x;
  int s = 0;
  for (int i = 0; i < 32; ++i) s += cnt[t * 32 + i];
  part[t] = s;
  __syncthreads();
  if (t == 0) {
    int run = 0;
    for (int i = 0; i < 256; ++i) { int v = part[i]; part[i] = run; run += v; }
    offs[NN] = run;
  }
  __syncthreads();
  int run = part[t];
  for (int i = 0; i < 32; ++i) {
    const int idx = t * 32 + i;
    offs[idx] = run;
    cursor[idx] = run;
    run += cnt[idx];
  }
}

__global__ __launch_bounds__(256) void k_fill(const int* __restrict__ edst,
                                              int* __restrict__ cursor,
                                              int* __restrict__ elist) {
  const int e = blockIdx.x * 256 + threadIdx.x;
  if (e < NE) {
    const int p = atomicAdd(&cursor[edst[e]], 1);
    elist[p] = e;
  }
}

// ---------------- per-edge bilinear GEMM: t[e][128] (and optional self[e][128]) ----
template <bool IS2>
__global__ __launch_bounds__(256) void k_msg(
    const float* __restrict__ u_, const float* __restrict__ cut_,
    const float* __restrict__ W1, const float* __restrict__ bvec,
    const float* __restrict__ W2, const float* __restrict__ feat16,
    const int* __restrict__ esrc, float* __restrict__ t_, float* __restrict__ self_) {
  __shared__ __align__(16) float hhL[64][65];
  __shared__ __align__(16) float nfL[64][17];
  __shared__ __align__(16) float BL[64][128];
  __shared__ float uL[64], cL[64];
  __shared__ int sL[64];
  const int tid = threadIdx.x;
  const int e0 = blockIdx.x * 64;
  if (tid < 64) {
    uL[tid] = u_[e0 + tid];
    cL[tid] = cut_[e0 + tid];
    sL[tid] = esrc[e0 + tid];
  }
  __syncthreads();
  for (int i = tid; i < 64 * 64; i += 256) {
    const int e = i >> 6, k = i & 63;
    hhL[e][k] = fmaxf(fmaf(uL[e], W1[k], bvec[k]), 0.f) * cL[e];
  }
  for (int i = tid; i < 64 * 16; i += 256) {
    const int e = i >> 4, f = i & 15;
    nfL[e][f] = feat16[(size_t)sL[e] * 16 + f];
  }
  const int ty = tid >> 4, tx = tid & 15;
  float acc[4][8];
#pragma unroll
  for (int a = 0; a < 4; ++a)
#pragma unroll
    for (int o = 0; o < 8; ++o) acc[a][o] = 0.f;

  for (int ch = 0; ch < 16; ++ch) {
    __syncthreads();
#pragma unroll
    for (int j = 0; j < 8; ++j) {
      const int q = tid + j * 256;
      const int row = q >> 5, c4 = (q & 31) << 2;
      const int kf = ch * 64 + row;
      size_t gaddr;
      if (IS2) gaddr = (size_t)(kf >> 4) * 2176 + (size_t)(kf & 15) * 128 + c4;
      else     gaddr = (size_t)kf * 128 + c4;
      *(float4*)&BL[row][c4] = *(const float4*)(W2 + gaddr);
    }
    __syncthreads();
#pragma unroll
    for (int kk = 0; kk < 4; ++kk) {
      const int k = ch * 4 + kk;
      float ha[4];
#pragma unroll
      for (int a = 0; a < 4; ++a) ha[a] = hhL[ty * 4 + a][k];
#pragma unroll
      for (int f = 0; f < 16; ++f) {
        float av[4];
#pragma unroll
        for (int a = 0; a < 4; ++a) av[a] = ha[a] * nfL[ty * 4 + a][f];
        const float* Br = &BL[kk * 16 + f][tx * 8];
#pragma unroll
        for (int o = 0; o < 8; ++o) {
          const float bv = Br[o];
#pragma unroll
          for (int a = 0; a < 4; ++a) acc[a][o] = fmaf(av[a], bv, acc[a][o]);
        }
      }
    }
  }
#pragma unroll
  for (int a = 0; a < 4; ++a) {
    float* op = &t_[(size_t)(e0 + ty * 4 + a) * 128 + tx * 8];
#pragma unroll
    for (int o = 0; o < 8; ++o) op[o] = acc[a][o] * 0.125f;  // 1/sqrt(F)/deg
  }

  if (IS2) {
    __syncthreads();
#pragma unroll
    for (int j = 0; j < 8; ++j) {
      const int q = tid + j * 256;
      const int row = q >> 5, c4 = (q & 31) << 2;
      *(float4*)&BL[row][c4] = *(const float4*)(W2 + (size_t)row * 2176 + 2048 + c4);
    }
    __syncthreads();
    float sacc[4][8];
#pragma unroll
    for (int a = 0; a < 4; ++a)
#pragma unroll
      for (int o = 0; o < 8; ++o) sacc[a][o] = 0.f;
    for (int k = 0; k < 64; ++k) {
      float ha[4];
#pragma unroll
      for (int a = 0; a < 4; ++a) ha[a] = hhL[ty * 4 + a][k];
      const float* Br = &BL[k][tx * 8];
#pragma unroll
      for (int o = 0; o < 8; ++o) {
        const float bv = Br[o];
#pragma unroll
        for (int a = 0; a < 4; ++a) sacc[a][o] = fmaf(ha[a], bv, sacc[a][o]);
      }
    }
#pragma unroll
    for (int a = 0; a < 4; ++a) {
      float* op = &self_[(size_t)(e0 + ty * 4 + a) * 128 + tx * 8];
#pragma unroll
      for (int o = 0; o < 8; ++o) op[o] = sacc[a][o] * 0.5f;  // 1/deg
    }
  }
}

// ---------------- gather (segment sum over incoming edges) + gate ----------------
__global__ __launch_bounds__(256) void k_gather1(
    const float* __restrict__ t_, const float* __restrict__ Y_,
    const int* __restrict__ offs, const int* __restrict__ elist,
    float* __restrict__ h1, float* __restrict__ h1s) {
  __shared__ float tL[128], YL[16], sG[32];
  const int n = blockIdx.x, tid = threadIdx.x;
  const int beg = offs[n], end = offs[n + 1];
  const int cc = tid & 15;
  const int lx = lidx_of(cc);
  const int o0 = ((tid >> 4) << 2) + lx;
  const int o1 = o0 + 64;
  float a0 = 0.f, a1 = 0.f;
  for (int ei = beg; ei < end; ++ei) {
    const int e = elist[ei];
    __syncthreads();
    if (tid < 128) tL[tid] = t_[(size_t)e * 128 + tid];
    else if (tid < 144) YL[tid - 128] = Y_[(size_t)e * 16 + tid - 128];
    __syncthreads();
    const float yv = YL[cc];
    a0 = fmaf(tL[o0], yv, a0);
    a1 = fmaf(tL[o1], yv, a1);
  }
  if (cc == 0) { sG[tid >> 4] = a0; sG[(tid >> 4) + 16] = a1; }
  __syncthreads();
  const float s0 = sG[tid >> 4], s1 = sG[(tid >> 4) + 16];
  const float r0 = (cc == 0) ? fmaxf(a0, 0.f) : a0 * (1.f / (1.f + expf(-s0)));
  const float r1 = (cc == 0) ? fmaxf(a1, 0.f) : a1 * (1.f / (1.f + expf(-s1)));
  h1[(size_t)n * 512 + tid] = r0;
  h1[(size_t)n * 512 + tid + 256] = r1;
  if ((tid & 31) == 0) {
    h1s[n * 16 + (tid >> 5)] = r0;       // g = 0..7  (p=0,c=0)
    h1s[n * 16 + (tid >> 5) + 8] = r1;   // g = 8..15
  }
}

__global__ __launch_bounds__(256) void k_gather2(
    const float* __restrict__ t_, const float* __restrict__ self_,
    const float* __restrict__ Y_, const float* __restrict__ h1,
    const int* __restrict__ offs, const int* __restrict__ elist,
    const int* __restrict__ esrc, float* __restrict__ h2) {
  __shared__ float tL[128], wL[128], YL[16], sG[32];
  const int n = blockIdx.x, tid = threadIdx.x;
  const int beg = offs[n], end = offs[n + 1];
  const int cc = tid & 15;
  const int lx = lidx_of(cc);
  const int o0 = ((tid >> 4) << 2) + lx;
  const int o1 = o0 + 64;
  float a0 = 0.f, a1 = 0.f;
  for (int ei = beg; ei < end; ++ei) {
    const int e = elist[ei];
    __syncthreads();
    if (tid < 128) tL[tid] = t_[(size_t)e * 128 + tid];
    else wL[tid - 128] = self_[(size_t)e * 128 + tid - 128];
    if (tid < 16) YL[tid] = Y_[(size_t)e * 16 + tid];
    __syncthreads();
    const int src = esrc[e];
    const float* hr = &h1[(size_t)src * 512];
    const float yv = YL[cc];
    a0 += tL[o0] * yv + hr[tid] * wL[o0];
    a1 += tL[o1] * yv + hr[tid + 256] * wL[o1];
  }
  if (cc == 0) { sG[tid >> 4] = a0; sG[(tid >> 4) + 16] = a1; }
  __syncthreads();
  const float s0 = sG[tid >> 4], s1 = sG[(tid >> 4) + 16];
  const float r0 = (cc == 0) ? fmaxf(a0, 0.f) : a0 * (1.f / (1.f + expf(-s0)));
  const float r1 = (cc == 0) ? fmaxf(a1, 0.f) : a1 * (1.f / (1.f + expf(-s1)));
  h2[(size_t)n * 512 + tid] = r0;
  h2[(size_t)n * 512 + tid + 256] = r1;
}

// ---------------- mean pool over each graph's 256 nodes ----------------
__global__ __launch_bounds__(256) void k_pool(const float* __restrict__ h2,
                                              float* __restrict__ enc) {
  const int b = blockIdx.x, tid = threadIdx.x;
  float a0 = 0.f, a1 = 0.f;
  for (int i = 0; i < 256; ++i) {
    const float* row = &h2[(size_t)(b * 256 + i) * 512];
    a0 += row[tid];
    a1 += row[tid + 256];
  }
  enc[b * 512 + tid] = a0 * (1.f / 256.f);
  enc[b * 512 + tid + 256] = a1 * (1.f / 256.f);
}

// ---------------- z = per-l linear mix of enc (B,32,16) -> (B,16,84) ----------------
__global__ __launch_bounds__(256) void k_zproj(const float* __restrict__ enc,
                                               const float* __restrict__ Wlin,
                                               float* __restrict__ z) {
  __shared__ float eL[512];
  const int b = blockIdx.x, tid = threadIdx.x;
  eL[tid] = enc[b * 512 + tid];
  eL[tid + 256] = enc[b * 512 + tid + 256];
  __syncthreads();
  for (int idx = tid; idx < 16 * 84; idx += 256) {
    const int g = idx / 84, d3 = idx % 84;
    int o0, m0, mo;
    if (d3 < 1)       { o0 = 0;  m0 = 1; mo = 0; }
    else if (d3 < 10) { o0 = 1;  m0 = 3; mo = 1; }
    else if (d3 < 35) { o0 = 10; m0 = 5; mo = 4; }
    else              { o0 = 35; m0 = 7; mo = 9; }
    const int rem = d3 - o0;
    const int jj = rem / m0;
    const int cc2 = rem - jj * m0;
    float a = 0.f;
    for (int mu = 0; mu < 32; ++mu)
      a = fmaf(eL[mu * 16 + mo + cc2], Wlin[(mu * 16 + g) * 16 + mo + jj], a);
    z[(size_t)(b * 16 + g) * 84 + d3] = a * 0.17677669529663687f;  // 1/sqrt(32)
  }
}

// ---------------- SO3 conv: per-l matmul ----------------
template <int M, int FI, int FO>
DEV void conv_item(const float* xL, const float* __restrict__ psi, int b, int g,
                   int o0, int j, float* __restrict__ out, float scale) {
  float acc[M];
#pragma unroll
  for (int c = 0; c < M; ++c) acc[c] = 0.f;
  for (int f = 0; f < FI; ++f) {
    const float* xr = &xL[f * 84 + o0];
    const float* pr = &psi[((size_t)f * FO + g) * 84 + o0 + j];
#pragma unroll
    for (int i = 0; i < M; ++i) {
      const float pv = pr[i * M];
#pragma unroll
      for (int c = 0; c < M; ++c) acc[c] = fmaf(xr[i * M + c], pv, acc[c]);
    }
  }
  float* op = &out[((size_t)b * FO + g) * 84 + o0 + j * M];
#pragma unroll
  for (int c = 0; c < M; ++c) op[c] = acc[c] * scale;
}

template <int FI, int FO>
__global__ __launch_bounds__(256) void k_conv(const float* __restrict__ x,
                                              const float* __restrict__ psi,
                                              float* __restrict__ out) {
  __shared__ float xL[FI * 84];
  const int tid = threadIdx.x, b = blockIdx.x;
  for (int i = tid; i < FI * 84; i += 256) xL[i] = x[(size_t)b * FI * 84 + i];
  __syncthreads();
  const int g0 = blockIdx.y * 16;
  if (tid < 16) {
    conv_item<1, FI, FO>(xL, psi, b, g0 + tid, 0, 0, out, 1.f / sqrtf((float)(FI * 1)));
  } else if (tid < 64) {
    const int q = tid - 16;
    conv_item<3, FI, FO>(xL, psi, b, g0 + q / 3, 1, q % 3, out, 1.f / sqrtf((float)(FI * 3)));
  } else if (tid < 144) {
    const int q = tid - 64;
    conv_item<5, FI, FO>(xL, psi, b, g0 + q / 5, 10, q % 5, out, 1.f / sqrtf((float)(FI * 5)));
  } else {
    const int q = tid - 144;
    conv_item<7, FI, FO>(xL, psi, b, g0 + q / 7, 35, q % 7, out, 1.f / sqrtf((float)(FI * 7)));
  }
}

// ---------------- SO3 act (fused, partial over g-splits) ----------------
// out_partial[gs][row][d] = sum over this split's g of relu(x@Gt)[row][g]*Gf[g][d]
// RB = 8 rows per block; 256 threads.
// phase1: thread owns 2 g-cols of a 512-col chunk, fa[8][2].
// phase2: 8 groups x 32 lanes; lane j accumulates acc[8 rows][3 dims] over its
//         group's 64 g-values; deterministic LDS tree reduce at block end.
template <int GSPLIT>
__global__ __launch_bounds__(256) void k_act_part(
    const float* __restrict__ x, const float* __restrict__ Gt,
    const float* __restrict__ Gf, float* __restrict__ part) {
  constexpr int RB = 8;
  constexpr int NCHUNK = 8 / GSPLIT;  // chunks of 512 g-cols
  __shared__ float sm[8 * RB * 32 * 3];  // 6144 floats; also holds y(672)+gch(8*516)
  float* yL = sm;          // [RB][84]
  float* gch = sm + 672;   // [RB][516]
  const int tid = threadIdx.x;
  const int gs = blockIdx.y;
  const int row0 = blockIdx.x * RB;
  const int nrows = gridDim.x * RB;

  for (int i = tid; i < RB * 84; i += 256) yL[i] = x[(size_t)row0 * 84 + i];

  const int gp = tid >> 5, j = tid & 31;
  float acc[RB][3];
#pragma unroll
  for (int r = 0; r < RB; ++r) {
    acc[r][0] = 0.f; acc[r][1] = 0.f; acc[r][2] = 0.f;
  }
  __syncthreads();

  for (int cc = gs * NCHUNK; cc < (gs + 1) * NCHUNK; ++cc) {
    const int g0 = cc * 512;
    // ---- phase 1: fa[r][2] = x rows @ Gt cols (tid, tid+256) of this chunk
    float fa[RB][2];
#pragma unroll
    for (int r = 0; r < RB; ++r) { fa[r][0] = 0.f; fa[r][1] = 0.f; }
    for (int dq = 0; dq < 21; ++dq) {
      float4 y4[RB];
      const float* yp = reinterpret_cast<const float*>(y4);
#pragma unroll
      for (int r = 0; r < RB; ++r) y4[r] = *(const float4*)&yL[r * 84 + dq * 4];
#pragma unroll
      for (int i = 0; i < 4; ++i) {
        const int d = dq * 4 + i;
        const float g0v = Gt[(size_t)d * 4096 + g0 + tid];
        const float g1v = Gt[(size_t)d * 4096 + g0 + 256 + tid];
#pragma unroll
        for (int r = 0; r < RB; ++r) {
          const float yv = yp[r * 4 + i];
          fa[r][0] = fmaf(yv, g0v, fa[r][0]);
          fa[r][1] = fmaf(yv, g1v, fa[r][1]);
        }
      }
    }
    __syncthreads();  // previous phase2 done reading gch
#pragma unroll
    for (int r = 0; r < RB; ++r) {
      gch[r * 516 + tid] = fmaxf(fa[r][0], 0.f);
      gch[r * 516 + tid + 256] = fmaxf(fa[r][1], 0.f);
    }
    __syncthreads();
    // ---- phase 2: this group's 64 g-values, 16 quads
    for (int q = 0; q < 16; ++q) {
      const int g2 = gp * 64 + q * 4;
      float4 gv[RB];
      const float* gvp = reinterpret_cast<const float*>(gv);
#pragma unroll
      for (int r = 0; r < RB; ++r) gv[r] = *(const float4*)&gch[r * 516 + g2];
#pragma unroll
      for (int i = 0; i < 4; ++i) {
        const size_t gidx = (size_t)(g0 + g2 + i) * 84;
        const float gf0 = Gf[gidx + j];
        const float gf1 = Gf[gidx + 32 + j];
        const float gf2 = (j < 20) ? Gf[gidx + 64 + j] : 0.f;
#pragma unroll
        for (int r = 0; r < RB; ++r) {
          const float pv = gvp[r * 4 + i];
          acc[r][0] = fmaf(pv, gf0, acc[r][0]);
          acc[r][1] = fmaf(pv, gf1, acc[r][1]);
          acc[r][2] = fmaf(pv, gf2, acc[r][2]);
        }
      }
    }
  }
  // ---- deterministic in-block reduce over the 8 groups
  __syncthreads();
#pragma unroll
  for (int r = 0; r < RB; ++r)
#pragma unroll
    for (int c = 0; c < 3; ++c)
      sm[((gp * RB + r) * 32 + j) * 3 + c] = acc[r][c];
  __syncthreads();
  for (int o = tid; o < RB * 84; o += 256) {
    const int r = o / 84, d = o % 84;
    const int jj = d & 31, c = d >> 5;
    float s = 0.f;
#pragma unroll
    for (int g = 0; g < 8; ++g) s += sm[((g * RB + r) * 32 + jj) * 3 + c];
    part[((size_t)gs * nrows + row0 + r) * 84 + d] = s;
  }
}

template <int GSPLIT>
__global__ __launch_bounds__(256) void k_act_reduce(const float* __restrict__ part,
                                                    float* __restrict__ out, int total) {
  const int i = blockIdx.x * 256 + threadIdx.x;
  if (i < total) {
    float s = part[i];
#pragma unroll
    for (int g = 1; g < GSPLIT; ++g) s += part[(size_t)g * total + i];
    out[i] = s * (1.f / (sqrtf(84.f) * 64.f));
  }
}

// ---------------- final: Ws2 contraction + orientation SH dot ----------------
__global__ __launch_bounds__(256) void k_final(const float* __restrict__ x,
                                               const float* __restrict__ Ws2,
                                               const float* __restrict__ orient,
                                               float* __restrict__ outp) {
  __shared__ float red[256][16];
  const int b = blockIdx.x, tid = threadIdx.x;
  const float* xr = &x[(size_t)(b * 256 + tid) * 84];
  const float* wr = &Ws2[tid * 16];
  float acc[16];
#pragma unroll
  for (int c = 0; c < 16; ++c) acc[c] = 0.f;
  acc[0] = fmaf(xr[0], wr[0], acc[0]);
#pragma unroll
  for (int i = 0; i < 3; ++i) {
    const float w = wr[1 + i];
#pragma unroll
    for (int c = 0; c < 3; ++c) acc[1 + c] = fmaf(xr[1 + i * 3 + c], w, acc[1 + c]);
  }
#pragma unroll
  for (int i = 0; i < 5; ++i) {
    const float w = wr[4 + i];
#pragma unroll
    for (int c = 0; c < 5; ++c) acc[4 + c] = fmaf(xr[10 + i * 5 + c], w, acc[4 + c]);
  }
#pragma unroll
  for (int i = 0; i < 7; ++i) {
    const float w = wr[9 + i];
#pragma unroll
    for (int c = 0; c < 7; ++c) acc[9 + c] = fmaf(xr[35 + i * 7 + c], w, acc[9 + c]);
  }
#pragma unroll
  for (int c = 0; c < 16; ++c) red[tid][c] = acc[c];
  __syncthreads();
  for (int off = 128; off > 0; off >>= 1) {
    if (tid < off)
#pragma unroll
      for (int c = 0; c < 16; ++c) red[tid][c] += red[tid + off][c];
    __syncthreads();
  }
  if (tid == 0) {
    const float aa = orient[b * 2 + 0], rr = orient[b * 2 + 1];
    float Y[16];
    real_sh_f(-sinf(aa) * cosf(rr), -sinf(aa) * sinf(rr), -cosf(aa), Y);
    const float sc1 = 1.f / 16.f;
    const float sc3 = 1.f / (16.f * 1.7320508075688772f);
    const float sc5 = 1.f / (16.f * 2.23606797749979f);
    const float sc7 = 1.f / (16.f * 2.6457513110645907f);
    float o = red[0][0] * sc1 * Y[0];
#pragma unroll
    for (int c = 1; c < 4; ++c) o += red[0][c] * sc3 * Y[c];
#pragma unroll
    for (int c = 4; c < 9; ++c) o += red[0][c] * sc5 * Y[c];
#pragma unroll
    for (int c = 9; c < 16; ++c) o += red[0][c] * sc7 * Y[c];
    outp[b] = o;
  }
}

extern "C" void kernel_launch(void* const* d_in, const int* in_sizes, int n_in,
                              void* d_out, int out_size, void* d_ws, size_t ws_size,
                              hipStream_t stream) {
  const float* node_feat = (const float*)d_in[0];
  const float* pos       = (const float*)d_in[1];
  const float* orient    = (const float*)d_in[2];
  const float* rad1_W1   = (const float*)d_in[3];
  const float* rad1_b    = (const float*)d_in[4];
  const float* rad1_W2   = (const float*)d_in[5];
  const float* rad2_W1   = (const float*)d_in[6];
  const float* rad2_b    = (const float*)d_in[7];
  const float* rad2_W2   = (const float*)d_in[8];
  const float* Wlin      = (const float*)d_in[9];
  const float* psi1      = (const float*)d_in[10];
  const float* psi2      = (const float*)d_in[11];
  const float* psi3      = (const float*)d_in[12];
  const float* G_to      = (const float*)d_in[13];
  const float* G_from    = (const float*)d_in[14];
  const float* Ws2       = (const float*)d_in[15];
  const int*   esrc      = (const int*)d_in[16];
  const int*   edst      = (const int*)d_in[17];

  float* w = (float*)d_ws;
  size_t off = 0;
  float* u_    = w + off; off += NE;
  float* cut_  = w + off; off += NE;
  float* Y_    = w + off; off += (size_t)NE * 16;
  float* t_    = w + off; off += (size_t)NE * 128;   // t1, then reused for t2
  float* self_ = w + off; off += (size_t)NE * 128;   // also reused as act partials
  float* h1    = w + off; off += (size_t)NN * 512;
  float* h1s   = w + off; off += (size_t)NN * 16;
  float* h2    = w + off; off += (size_t)NN * 512;
  float* enc   = w + off; off += (size_t)NB * 512;
  float* z     = w + off; off += (size_t)NB * 16 * 84;
  float* xb1   = w + off; off += (size_t)NB * 256 * 84;
  float* xb2   = w + off; off += (size_t)NB * 256 * 84;
  int* cnt    = (int*)(w + off); off += NN;
  int* offs   = (int*)(w + off); off += NN + 1;
  int* cursor = (int*)(w + off); off += NN;
  int* elist  = (int*)(w + off); off += NE;

  float* part = self_;  // dead after k_gather2; 4x2048x84 etc fit in NE*128

  hipMemsetAsync(cnt, 0, NN * sizeof(int), stream);
  k_edge_prep<<<NE / 256, 256, 0, stream>>>(pos, esrc, edst, u_, cut_, Y_, cnt);
  k_scan<<<1, 256, 0, stream>>>(cnt, offs, cursor);
  k_fill<<<NE / 256, 256, 0, stream>>>(edst, cursor, elist);
  k_msg<false><<<NE / 64, 256, 0, stream>>>(u_, cut_, rad1_W1, rad1_b, rad1_W2,
                                            node_feat, esrc, t_, nullptr);
  k_gather1<<<NN, 256, 0, stream>>>(t_, Y_, offs, elist, h1, h1s);
  k_msg<true><<<NE / 64, 256, 0, stream>>>(u_, cut_, rad2_W1, rad2_b, rad2_W2,
                                           h1s, esrc, t_, self_);
  k_gather2<<<NN, 256, 0, stream>>>(t_, self_, Y_, h1, offs, elist, esrc, h2);
  k_pool<<<NB, 256, 0, stream>>>(h2, enc);
  k_zproj<<<NB, 256, 0, stream>>>(enc, Wlin, z);

  k_conv<16, 64><<<dim3(NB, 4), 256, 0, stream>>>(z, psi1, xb1);
  k_act_part<4><<<dim3(2048 / 8, 4), 256, 0, stream>>>(xb1, G_to, G_from, part);
  k_act_reduce<4><<<(2048 * 84 + 255) / 256, 256, 0, stream>>>(part, xb2, 2048 * 84);

  k_conv<64, 128><<<dim3(NB, 8), 256, 0, stream>>>(xb2, psi2, xb1);
  k_act_part<2><<<dim3(4096 / 8, 2), 256, 0, stream>>>(xb1, G_to, G_from, part);
  k_act_reduce<2><<<(4096 * 84 + 255) / 256, 256, 0, stream>>>(part, xb2, 4096 * 84);

  k_conv<128, 256><<<dim3(NB, 16), 256, 0, stream>>>(xb2, psi3, xb1);
  k_act_part<1><<<dim3(8192 / 8, 1), 256, 0, stream>>>(xb1, G_to, G_from, part);
  k_act_reduce<1><<<(8192 * 84 + 255) / 256, 256, 0, stream>>>(part, xb2, 8192 * 84);

  k_final<<<NB, 256, 0, stream>>>(xb2, Ws2, orient, (float*)d_out);
}